// Round 1
// baseline (307.801 us; speedup 1.0000x reference)
//
#include <hip/hip_runtime.h>

#define DD 128
#define BSH 7
#define LSTR 136   // LDS row stride in bf16 elems: 272B -> 2-way bank alias max (free)
#define WSTR 136   // weight LDS row stride, same balanced bank pattern

typedef __attribute__((ext_vector_type(8))) short bf16x8;
typedef __attribute__((ext_vector_type(4))) float f32x4;

__device__ __forceinline__ unsigned short f2b(float f){
  unsigned u = __builtin_bit_cast(unsigned, f);
  u += 0x7FFFu + ((u >> 16) & 1u);            // round-to-nearest-even
  return (unsigned short)(u >> 16);
}
__device__ __forceinline__ float blo(unsigned u){ return __builtin_bit_cast(float, u << 16); }
__device__ __forceinline__ float bhi(unsigned u){ return __builtin_bit_cast(float, u & 0xFFFF0000u); }
__device__ __forceinline__ float b2f(unsigned short h){ return __builtin_bit_cast(float, ((unsigned)h) << 16); }
__device__ __forceinline__ unsigned pk2(float a, float b){
  return (unsigned)f2b(a) | ((unsigned)f2b(b) << 16);
}

// ---------------- fused pre: convert x,t -> bf16 | weight transpose | bucket hist ----------------
struct WP { const float* w[7]; };
__global__ __launch_bounds__(256) void k_pre(const float* __restrict__ x,
    const float* __restrict__ t, unsigned* __restrict__ xh, unsigned* __restrict__ th,
    int M, WP p, unsigned short* __restrict__ wt,
    const int* __restrict__ e_t, const int* __restrict__ e_xct,
    int* __restrict__ gbcount, int E, int NBper, int ncv){
  const int bid = blockIdx.x;
  if (bid < ncv){
    int tid = bid*256 + threadIdx.x;
    if (tid < M){
      float4 v = ((const float4*)x)[tid];
      ((uint2*)xh)[tid] = make_uint2(pk2(v.x, v.y), pk2(v.z, v.w));
    } else if (tid < 2*M){
      int k = tid - M;
      float4 v = ((const float4*)t)[k];
      ((uint2*)th)[k] = make_uint2(pk2(v.x, v.y), pk2(v.z, v.w));
    }
    return;
  }
  if (bid < ncv + 7){
    const float* W = p.w[bid - ncv];
    unsigned short* dst = wt + (size_t)(bid - ncv)*DD*DD;
    for (int e = threadIdx.x; e < DD*DD; e += 256){
      int k = e >> 7, c = e & 127;
      dst[c*DD + k] = f2b(W[e]);
    }
    return;
  }
  // bucket histogram (256 virtual blocks)
  __shared__ int h[800];
  const int vb = bid - ncv - 7;
  const int NB2 = 2*NBper;
  for (int i = threadIdx.x; i < NB2; i += 256) h[i] = 0;
  __syncthreads();
  const long total = 2L*E;
  for (long idx = (long)vb*256 + threadIdx.x; idx < total; idx += 65536L){
    int s = idx >= E;
    int e = (int)(idx - (s ? (long)E : 0));
    int d = (s ? e_xct : e_t)[E + e];
    atomicAdd(&h[s*NBper + (d >> BSH)], 1);
  }
  __syncthreads();
  for (int i = threadIdx.x; i < NB2; i += 256)
    if (h[i]) atomicAdd(&gbcount[i], h[i]);
}

// ---------------- scan bucket counts -> bases, init cursors ----------------
__global__ void k_bscan(const int* __restrict__ gbcount, int* __restrict__ gbase,
                        int* __restrict__ gcursor, int NB2, int total){
  __shared__ int sm[1024];
  const int t = threadIdx.x;
  int v = (t < NB2) ? gbcount[t] : 0;
  sm[t] = v; __syncthreads();
  for (int d = 1; d < 1024; d <<= 1){
    int u = (t >= d) ? sm[t-d] : 0;
    __syncthreads();
    sm[t] += u;
    __syncthreads();
  }
  if (t < NB2){ int ex = sm[t] - v; gbase[t] = ex; gcursor[t] = ex; }
  if (t == 0) gbase[NB2] = total;
}

// ---------------- scatter edges into coarse buckets (packed src|dst<<16) ----------------
#define SCCH 8192
__global__ __launch_bounds__(256) void k_scatter(const int* __restrict__ e_t,
    const int* __restrict__ e_xct, int* __restrict__ gcursor,
    unsigned* __restrict__ gbucket, int E, int NBper){
  __shared__ int cnt[800]; __shared__ int gpos[800]; __shared__ int cur[800];
  const int NB2 = 2*NBper;
  const int t = threadIdx.x;
  for (int i = t; i < NB2; i += 256){ cnt[i] = 0; cur[i] = 0; }
  __syncthreads();
  const long base = (long)blockIdx.x * SCCH;
  const long end  = min(base + SCCH, 2L*E);
  for (long idx = base + t; idx < end; idx += 256){
    int s = idx >= E;
    int e = (int)(idx - (s ? (long)E : 0));
    int d = (s ? e_xct : e_t)[E + e];
    atomicAdd(&cnt[s*NBper + (d >> BSH)], 1);
  }
  __syncthreads();
  for (int i = t; i < NB2; i += 256)
    if (cnt[i]) gpos[i] = atomicAdd(&gcursor[i], cnt[i]);
  __syncthreads();
  for (long idx = base + t; idx < end; idx += 256){
    int s = idx >= E;
    int e = (int)(idx - (s ? (long)E : 0));
    const int* ei = s ? e_xct : e_t;
    int sv = ei[e];
    int d  = ei[E + e];
    int b  = s*NBper + (d >> BSH);
    int pos = atomicAdd(&cur[b], 1);
    gbucket[gpos[b] + pos] = (unsigned)sv | ((unsigned)d << 16);
  }
}

// ---------------- per-bucket: bin by exact destination, write offs + csr ----------------
__global__ __launch_bounds__(256) void k_build(const unsigned* __restrict__ gbucket,
    const int* __restrict__ gbase, int* __restrict__ offs,
    unsigned short* __restrict__ csr, int N, int E, int NBper){
  __shared__ int cnt[128]; __shared__ int pre[128]; __shared__ int cur[128];
  const int b  = blockIdx.x;
  const int s  = b >= NBper;
  const int bb = b - s*NBper;
  const int d0 = bb << BSH;
  const int t  = threadIdx.x;
  if (t < 128) cnt[t] = 0;
  __syncthreads();
  const int g0 = gbase[b], g1 = gbase[b+1];
  for (int j = g0 + t; j < g1; j += 256){
    unsigned en = gbucket[j];
    atomicAdd(&cnt[(en >> 16) & 127], 1);
  }
  __syncthreads();
  int v = (t < 128) ? cnt[t] : 0;
  if (t < 128) pre[t] = v;
  __syncthreads();
  for (int d = 1; d < 128; d <<= 1){
    int u = (t >= d && t < 128) ? pre[t-d] : 0;
    __syncthreads();
    if (t < 128) pre[t] += u;
    __syncthreads();
  }
  if (t < 128){
    int ex = pre[t] - v;
    cur[t] = ex;
    int dd = d0 + t;
    if (dd < N) offs[(size_t)s*(N+1) + dd] = (g0 - s*E) + ex;
  }
  if (t == 128 + 0 && bb == NBper-1) offs[(size_t)s*(N+1) + N] = E;
  __syncthreads();
  for (int j = g0 + t; j < g1; j += 256){
    unsigned en = gbucket[j];
    int d7 = (en >> 16) & 127;
    int pos = atomicAdd(&cur[d7], 1);
    csr[(size_t)g0 + pos] = (unsigned short)(en & 0xFFFFu);
  }
}

// ---------------- gather-aggregate: hA = t + segsum_A(t), hB = t + segsum_B(x) ----------------
__global__ __launch_bounds__(256) void k_gather(const unsigned short* __restrict__ th,
    const unsigned short* __restrict__ xh, const int* __restrict__ offs,
    const unsigned short* __restrict__ csr, unsigned short* hA, unsigned short* hB,
    int N, int E){
  const int w = threadIdx.x >> 6, l = threadIdx.x & 63;
  const long wid = (long)blockIdx.x*4 + w;
  if (wid >= 2L*N) return;
  const int s = wid >= N;
  const int i = (int)(wid - (s ? N : 0));
  const int* off = offs + (size_t)s*(N+1);
  const unsigned short* src = s ? xh : th;
  const unsigned short* cs = csr + (size_t)s*E;
  const int o0 = off[i], o1 = off[i+1];
  const int deg = o1 - o0;
  const int rs = l >> 4;
  const int q  = l & 15;
  float a0=0,a1=0,a2=0,a3=0,a4=0,a5=0,a6=0,a7=0;
  if (deg > 0){
    int ce = cs[o0 + (l < deg ? l : deg-1)];
    for (int base = 0; base < deg; base += 64){
      const int nb = min(64, deg - base);
      const int ce_cur = ce;
      const int nxt = base + 64;
      if (nxt < deg){
        const int rem2 = deg - nxt;
        ce = cs[o0 + nxt + (l < rem2 ? l : rem2-1)];   // prefetch next window
      }
      for (int jj = 0; jj < nb; jj += 16){
        #pragma unroll
        for (int u4 = 0; u4 < 4; ++u4){
          const int idx = jj + u4*4 + rs;
          const int r = __shfl(ce_cur, idx < nb ? idx : nb-1);  // uniform, clamped
          uint4 v = *(const uint4*)(src + (size_t)r*DD + q*8);
          const unsigned m = (idx < nb) ? 0xFFFFFFFFu : 0u;
          v.x &= m; v.y &= m; v.z &= m; v.w &= m;
          a0+=blo(v.x); a1+=bhi(v.x); a2+=blo(v.y); a3+=bhi(v.y);
          a4+=blo(v.z); a5+=bhi(v.z); a6+=blo(v.w); a7+=bhi(v.w);
        }
      }
    }
  }
  a0 += __shfl_xor(a0,16); a1 += __shfl_xor(a1,16);
  a2 += __shfl_xor(a2,16); a3 += __shfl_xor(a3,16);
  a4 += __shfl_xor(a4,16); a5 += __shfl_xor(a5,16);
  a6 += __shfl_xor(a6,16); a7 += __shfl_xor(a7,16);
  a0 += __shfl_xor(a0,32); a1 += __shfl_xor(a1,32);
  a2 += __shfl_xor(a2,32); a3 += __shfl_xor(a3,32);
  a4 += __shfl_xor(a4,32); a5 += __shfl_xor(a5,32);
  a6 += __shfl_xor(a6,32); a7 += __shfl_xor(a7,32);
  if (l < 16){
    uint4 tv = *(const uint4*)(th + (size_t)i*DD + q*8);
    a0+=blo(tv.x); a1+=bhi(tv.x); a2+=blo(tv.y); a3+=bhi(tv.y);
    a4+=blo(tv.z); a5+=bhi(tv.z); a6+=blo(tv.w); a7+=bhi(tv.w);
    uint4 o;
    o.x = pk2(a0,a1); o.y = pk2(a2,a3); o.z = pk2(a4,a5); o.w = pk2(a6,a7);
    *(uint4*)((s ? hB : hA) + (size_t)i*DD + q*8) = o;
  }
}

// ================= fused GEMM-chain machinery =================
// A frag: row = lane&15, k = 8*(lane>>4)+j ; C/D: col = lane&15, row = 4*(lane>>4)+reg
// B operand now read from LDS-staged weight tile (wlds, WSTR stride).

// ---- weight staging: issue-early (global->reg), write-late (reg->LDS) ----
// 128x128 bf16 = 16384 elems = 2048 uint4 chunks; 256 threads x 8 chunks.
__device__ __forceinline__ void stage_load(uint4 ws[8], const unsigned short* __restrict__ Wt){
  const int tid = threadIdx.x;
  #pragma unroll
  for (int i = 0; i < 8; ++i){
    ws[i] = *(const uint4*)(Wt + (size_t)(i*256 + tid)*8);
  }
}
__device__ __forceinline__ void stage_write(const uint4 ws[8], unsigned short* wlds){
  const int tid = threadIdx.x;
  #pragma unroll
  for (int i = 0; i < 8; ++i){
    int e8 = i*256 + tid;
    int r = e8 >> 4;           // 16 chunks (128 elems) per row
    int c = (e8 & 15) * 8;
    *(uint4*)(wlds + r*WSTR + c) = ws[i];
  }
}

__device__ __forceinline__ void gemm_global(const unsigned short* __restrict__ X,
    int rbase, int c0, int g, const unsigned short* wlds,
    f32x4 acc[8], int N){
  int arow = rbase + c0; if (arow > N-1) arow = N-1;
  const unsigned short* ap = X + (size_t)arow*DD + g*8;
  #pragma unroll
  for (int kb = 0; kb < 4; ++kb){
    bf16x8 a = *(const bf16x8*)(ap + kb*32);
    #pragma unroll
    for (int cb = 0; cb < 8; ++cb){
      bf16x8 b = *(const bf16x8*)(wlds + (cb*16 + c0)*WSTR + kb*32 + g*8);
      acc[cb] = __builtin_amdgcn_mfma_f32_16x16x32_bf16(a, b, acc[cb], 0, 0, 0);
    }
  }
}

__device__ __forceinline__ void gemm_lds(const unsigned short* lds,
    int w, int c0, int g, const unsigned short* wlds, f32x4 acc[8]){
  const unsigned short* ap = lds + (w*16 + c0)*LSTR + g*8;
  #pragma unroll
  for (int kb = 0; kb < 4; ++kb){
    bf16x8 a = *(const bf16x8*)(ap + kb*32);
    #pragma unroll
    for (int cb = 0; cb < 8; ++cb){
      bf16x8 b = *(const bf16x8*)(wlds + (cb*16 + c0)*WSTR + kb*32 + g*8);
      acc[cb] = __builtin_amdgcn_mfma_f32_16x16x32_bf16(a, b, acc[cb], 0, 0, 0);
    }
  }
}

// ---------- t-branch chain (5 GEMMs) as device fn ----------
__device__ __forceinline__ void chainT_body(unsigned short* lds, unsigned short* wlds,
    int bid,
    const unsigned short* __restrict__ hA, const unsigned short* __restrict__ hB,
    const unsigned short* __restrict__ W1a, const float* __restrict__ b1a,
    const unsigned short* __restrict__ W2a, const float* __restrict__ b2a,
    const unsigned short* __restrict__ W1b, const float* __restrict__ b1b,
    const unsigned short* __restrict__ W2b, const float* __restrict__ b2b,
    const unsigned short* __restrict__ Wo,  const float* __restrict__ bo,
    const unsigned short* __restrict__ th,
    const float* __restrict__ lng, const float* __restrict__ lnb,
    float* __restrict__ outT, int N)
{
  const int tid = threadIdx.x;
  const int w = tid >> 6, l = tid & 63;
  const int g = l >> 4, c0 = l & 15;
  const int rbase = bid*64 + w*16;

  f32x4 acc[8];
  uint4 ws[8];

  // stage W1a (exposed once per block)
  stage_load(ws, W1a);
  stage_write(ws, wlds);
  __syncthreads();

  // ---- GEMM 1: hA @ W1a  (prefetch W2a under it) ----
  stage_load(ws, W2a);
  #pragma unroll
  for (int cb = 0; cb < 8; ++cb) acc[cb] = 0.f;
  gemm_global(hA, rbase, c0, g, wlds, acc, N);
  #pragma unroll
  for (int cb = 0; cb < 8; ++cb){
    float bv = b1a[cb*16 + c0];
    #pragma unroll
    for (int r = 0; r < 4; ++r)
      lds[(w*16 + 4*g + r)*LSTR + cb*16 + c0] = f2b(fmaxf(acc[cb][r] + bv, 0.f));
  }
  __syncthreads();
  stage_write(ws, wlds);
  __syncthreads();

  // ---- GEMM 2: h @ W2a -> pAv  (prefetch W1b) ----
  stage_load(ws, W1b);
  #pragma unroll
  for (int cb = 0; cb < 8; ++cb) acc[cb] = 0.f;
  gemm_lds(lds, w, c0, g, wlds, acc);
  float pAv[8][4];
  #pragma unroll
  for (int cb = 0; cb < 8; ++cb){
    float bv = b2a[cb*16 + c0];
    #pragma unroll
    for (int r = 0; r < 4; ++r) pAv[cb][r] = acc[cb][r] + bv;
  }
  __syncthreads();
  stage_write(ws, wlds);
  __syncthreads();

  // ---- GEMM 3: hB @ W1b  (prefetch W2b) ----
  stage_load(ws, W2b);
  #pragma unroll
  for (int cb = 0; cb < 8; ++cb) acc[cb] = 0.f;
  gemm_global(hB, rbase, c0, g, wlds, acc, N);
  #pragma unroll
  for (int cb = 0; cb < 8; ++cb){
    float bv = b1b[cb*16 + c0];
    #pragma unroll
    for (int r = 0; r < 4; ++r)
      lds[(w*16 + 4*g + r)*LSTR + cb*16 + c0] = f2b(fmaxf(acc[cb][r] + bv, 0.f));
  }
  __syncthreads();
  stage_write(ws, wlds);
  __syncthreads();

  // ---- GEMM 4: h @ W2b -> t2  (prefetch Wo) ----
  stage_load(ws, Wo);
  #pragma unroll
  for (int cb = 0; cb < 8; ++cb) acc[cb] = 0.f;
  gemm_lds(lds, w, c0, g, wlds, acc);

  float t2f[8][4];
  #pragma unroll
  for (int cb = 0; cb < 8; ++cb){
    float bv = b2b[cb*16 + c0];
    #pragma unroll
    for (int r = 0; r < 4; ++r){
      int orow = rbase + 4*g + r;
      int rc = orow > N-1 ? N-1 : orow;
      size_t oi = (size_t)rc*DD + cb*16 + c0;
      float v = fmaxf(acc[cb][r] + bv + b2f(th[oi]) + pAv[cb][r], 0.f);
      t2f[cb][r] = v;
      lds[(w*16 + 4*g + r)*LSTR + cb*16 + c0] = f2b(v);
    }
  }
  __syncthreads();
  stage_write(ws, wlds);
  __syncthreads();

  // ---- GEMM 5: t2 @ Wo + LN + residual ----
  #pragma unroll
  for (int cb = 0; cb < 8; ++cb) acc[cb] = 0.f;
  gemm_lds(lds, w, c0, g, wlds, acc);

  float u[8][4];
  float sm_[4] = {0,0,0,0}, sq_[4] = {0,0,0,0};
  #pragma unroll
  for (int cb = 0; cb < 8; ++cb){
    float bv = bo[cb*16 + c0];
    #pragma unroll
    for (int r = 0; r < 4; ++r){
      float v = fmaxf(acc[cb][r] + bv, 0.f);
      u[cb][r] = v;
      sm_[r] += v; sq_[r] += v*v;
    }
  }
  #pragma unroll
  for (int m = 1; m < 16; m <<= 1){
    #pragma unroll
    for (int r = 0; r < 4; ++r){
      sm_[r] += __shfl_xor(sm_[r], m, 64);
      sq_[r] += __shfl_xor(sq_[r], m, 64);
    }
  }
  float mean[4], rstd[4];
  #pragma unroll
  for (int r = 0; r < 4; ++r){
    mean[r] = sm_[r] * (1.0f/DD);
    float var = sq_[r] * (1.0f/DD) - mean[r]*mean[r];
    rstd[r] = rsqrtf(var + 1e-5f);
  }
  #pragma unroll
  for (int cb = 0; cb < 8; ++cb){
    float gv = lng[cb*16 + c0], bv2 = lnb[cb*16 + c0];
    #pragma unroll
    for (int r = 0; r < 4; ++r){
      int orow = rbase + 4*g + r;
      if (orow < N){
        size_t oi = (size_t)orow*DD + cb*16 + c0;
        outT[oi] = (u[cb][r] - mean[r]) * rstd[r] * gv + bv2 + t2f[cb][r];
      }
    }
  }
}

// ---------- fc_x MLP as device fn ----------
__device__ __forceinline__ void mlp2_body(unsigned short* lds, unsigned short* wlds,
    int bid,
    const unsigned short* __restrict__ X,
    const unsigned short* __restrict__ W1, const float* __restrict__ b1,
    const unsigned short* __restrict__ W2, const float* __restrict__ b2,
    const unsigned short* __restrict__ resh, float* __restrict__ outF, int N)
{
  const int tid = threadIdx.x;
  const int w = tid >> 6, l = tid & 63;
  const int g = l >> 4, c0 = l & 15;
  const int rbase = bid*64 + w*16;

  f32x4 acc[8];
  uint4 ws[8];

  stage_load(ws, W1);
  stage_write(ws, wlds);
  __syncthreads();

  // ---- GEMM 1 (prefetch W2 under it) ----
  stage_load(ws, W2);
  #pragma unroll
  for (int cb = 0; cb < 8; ++cb) acc[cb] = 0.f;
  gemm_global(X, rbase, c0, g, wlds, acc, N);

  #pragma unroll
  for (int cb = 0; cb < 8; ++cb){
    float bv = b1[cb*16 + c0];
    #pragma unroll
    for (int r = 0; r < 4; ++r)
      lds[(w*16 + 4*g + r)*LSTR + cb*16 + c0] = f2b(fmaxf(acc[cb][r] + bv, 0.f));
  }
  __syncthreads();
  stage_write(ws, wlds);
  __syncthreads();

  // ---- GEMM 2 ----
  #pragma unroll
  for (int cb = 0; cb < 8; ++cb) acc[cb] = 0.f;
  gemm_lds(lds, w, c0, g, wlds, acc);

  #pragma unroll
  for (int cb = 0; cb < 8; ++cb){
    float bv = b2[cb*16 + c0];
    #pragma unroll
    for (int r = 0; r < 4; ++r){
      int orow = rbase + 4*g + r;
      if (orow < N){
        size_t oi = (size_t)orow*DD + cb*16 + c0;
        outF[oi] = acc[cb][r] + bv + b2f(resh[oi]);
      }
    }
  }
}

// ---------- fused tail: [0,gg) chainT ; [gg,2gg) fc_x ----------
__global__ __launch_bounds__(256) void k_tail(
    const unsigned short* __restrict__ hA, const unsigned short* __restrict__ hB,
    const unsigned short* __restrict__ xh, const unsigned short* __restrict__ th,
    const unsigned short* __restrict__ wt,
    const float* __restrict__ b1a, const float* __restrict__ b2a,
    const float* __restrict__ b1b, const float* __restrict__ b2b,
    const float* __restrict__ bo,  const float* __restrict__ lng,
    const float* __restrict__ lnb, const float* __restrict__ bf1,
    const float* __restrict__ bf2,
    float* __restrict__ outX, float* __restrict__ outT, int N, int gg)
{
  __shared__ unsigned short lds[64*LSTR];     // 17408 B  A/intermediate tiles (per-wave private rows)
  __shared__ unsigned short wlds[128*WSTR];   // 34816 B  block-shared weight tile
  const unsigned short* W1a = wt + 0*DD*DD;
  const unsigned short* W2a = wt + 1*DD*DD;
  const unsigned short* W1b = wt + 2*DD*DD;
  const unsigned short* W2b = wt + 3*DD*DD;
  const unsigned short* Wo  = wt + 4*DD*DD;
  const unsigned short* Wf1 = wt + 5*DD*DD;
  const unsigned short* Wf2 = wt + 6*DD*DD;
  if (blockIdx.x < (unsigned)gg){
    chainT_body(lds, wlds, blockIdx.x, hA, hB, W1a, b1a, W2a, b2a, W1b, b1b, W2b, b2b,
                Wo, bo, th, lng, lnb, outT, N);
  } else {
    mlp2_body(lds, wlds, blockIdx.x - gg, xh, Wf1, bf1, Wf2, bf2, xh, outX, N);
  }
}

extern "C" void kernel_launch(void* const* d_in, const int* in_sizes, int n_in,
                              void* d_out, int out_size, void* d_ws, size_t ws_size,
                              hipStream_t stream) {
  const float* x     = (const float*)d_in[0];
  const float* t     = (const float*)d_in[1];
  const int*   e_t   = (const int*)d_in[2];
  const int*   e_xct = (const int*)d_in[3];
  const float* b1a = (const float*)d_in[5];
  const float* b2a = (const float*)d_in[7];
  const float* b1b = (const float*)d_in[9];
  const float* b2b = (const float*)d_in[11];
  const float* bo  = (const float*)d_in[13];
  const float* lng = (const float*)d_in[14];
  const float* lnb = (const float*)d_in[15];
  const float* bf1 = (const float*)d_in[17];
  const float* bf2 = (const float*)d_in[19];

  const int N = in_sizes[0] / DD;     // 50000
  const int E = in_sizes[2] / 2;      // 1600000
  const int NBper = (N + 127) >> BSH; // 391
  const int NB2 = 2*NBper;            // 782

  // ---- workspace carve ----
  char* p = (char*)d_ws;
  auto carve = [&](size_t b)->char*{ char* r = p; p += (b + 255) & ~(size_t)255; return r; };
  size_t nd2 = (size_t)N*DD*2, nd4 = (size_t)N*DD*4;
  unsigned short* xh = (unsigned short*)carve(nd2);
  unsigned short* th = (unsigned short*)carve(nd2);
  unsigned short* hA = (unsigned short*)carve(nd2);
  unsigned short* hB = (unsigned short*)carve(nd2);
  float*          pA = (float*)carve(nd4);            // gbucket alias only
  unsigned short* wt = (unsigned short*)carve((size_t)7*DD*DD*2);
  int* gbcount = (int*)carve((size_t)NB2*4);
  int* gbase   = (int*)carve((size_t)(NB2+1)*4);
  int* gcursor = (int*)carve((size_t)NB2*4);
  int* offs    = (int*)carve((size_t)2*(N+1)*4);
  unsigned short* csr = (unsigned short*)carve((size_t)2*E*2);
  unsigned* gbucket = (unsigned*)pA;                  // 2E*4 = 12.8MB <= nd4 (25.6MB)

  float* outX = (float*)d_out;
  float* outT = outX + (size_t)N*DD;

  hipMemsetAsync(gbcount, 0, (size_t)NB2*4, stream);

  WP wp;
  wp.w[0] = (const float*)d_in[4];  wp.w[1] = (const float*)d_in[6];
  wp.w[2] = (const float*)d_in[8];  wp.w[3] = (const float*)d_in[10];
  wp.w[4] = (const float*)d_in[12]; wp.w[5] = (const float*)d_in[16];
  wp.w[6] = (const float*)d_in[18];

  const int M4 = N*DD/4;
  const int ncv = (2*M4 + 255)/256;
  k_pre<<<ncv + 7 + 256, 256, 0, stream>>>(x, t, (unsigned*)xh, (unsigned*)th, M4,
                                           wp, wt, e_t, e_xct, gbcount, E, NBper, ncv);
  k_bscan<<<1, 1024, 0, stream>>>(gbcount, gbase, gcursor, NB2, 2*E);
  const int nsc = (int)((2L*E + SCCH-1) / SCCH);
  k_scatter<<<nsc, 256, 0, stream>>>(e_t, e_xct, gcursor, gbucket, E, NBper);
  k_build<<<NB2, 256, 0, stream>>>(gbucket, gbase, offs, csr, N, E, NBper);
  k_gather<<<(2*N + 3)/4, 256, 0, stream>>>(th, xh, offs, csr, hA, hB, N, E);

  const int gg = (N + 63)/64;
  k_tail<<<2*gg, 256, 0, stream>>>(hA, hB, xh, th, wt, b1a, b2a, b1b, b2b, bo,
                                   lng, lnb, bf1, bf2, outX, outT, N, gg);
}

// Round 2
// 233.268 us; speedup vs baseline: 1.3195x; 1.3195x over previous
//
#include <hip/hip_runtime.h>

#define DD 128
#define BSH 7
#define LSTR 136   // h-tile LDS row stride in bf16 elems: 272B -> 2-way bank alias max (free)

typedef __attribute__((ext_vector_type(8))) short bf16x8;
typedef __attribute__((ext_vector_type(4))) float f32x4;

__device__ __forceinline__ unsigned short f2b(float f){
  unsigned u = __builtin_bit_cast(unsigned, f);
  u += 0x7FFFu + ((u >> 16) & 1u);            // round-to-nearest-even
  return (unsigned short)(u >> 16);
}
__device__ __forceinline__ float blo(unsigned u){ return __builtin_bit_cast(float, u << 16); }
__device__ __forceinline__ float bhi(unsigned u){ return __builtin_bit_cast(float, u & 0xFFFF0000u); }
__device__ __forceinline__ float b2f(unsigned short h){ return __builtin_bit_cast(float, ((unsigned)h) << 16); }
__device__ __forceinline__ unsigned pk2(float a, float b){
  return (unsigned)f2b(a) | ((unsigned)f2b(b) << 16);
}

// ---------------- fused pre: convert x,t -> bf16 | weight transpose (XOR-swizzled) | bucket hist ----------------
// Weight image: W^T row-major 128x128 bf16, element (row=c, col=k) stored at
// index (c*128 + k) ^ ((c&7)<<3)  -- byte ^ ((row&7)<<4), the G4 swizzle.
// global_load_lds copies this image linearly to LDS; ds_read applies same XOR.
struct WP { const float* w[7]; };
__global__ __launch_bounds__(256) void k_pre(const float* __restrict__ x,
    const float* __restrict__ t, unsigned* __restrict__ xh, unsigned* __restrict__ th,
    int M, WP p, unsigned short* __restrict__ wt,
    const int* __restrict__ e_t, const int* __restrict__ e_xct,
    int* __restrict__ gbcount, int E, int NBper, int ncv){
  const int bid = blockIdx.x;
  if (bid < ncv){
    int tid = bid*256 + threadIdx.x;
    if (tid < M){
      float4 v = ((const float4*)x)[tid];
      ((uint2*)xh)[tid] = make_uint2(pk2(v.x, v.y), pk2(v.z, v.w));
    } else if (tid < 2*M){
      int k = tid - M;
      float4 v = ((const float4*)t)[k];
      ((uint2*)th)[k] = make_uint2(pk2(v.x, v.y), pk2(v.z, v.w));
    }
    return;
  }
  if (bid < ncv + 7){
    const float* W = p.w[bid - ncv];
    unsigned short* dst = wt + (size_t)(bid - ncv)*DD*DD;
    for (int e = threadIdx.x; e < DD*DD; e += 256){
      int k = e >> 7, c = e & 127;
      dst[(c*DD + k) ^ ((c & 7) << 3)] = f2b(W[e]);
    }
    return;
  }
  // bucket histogram (256 virtual blocks)
  __shared__ int h[800];
  const int vb = bid - ncv - 7;
  const int NB2 = 2*NBper;
  for (int i = threadIdx.x; i < NB2; i += 256) h[i] = 0;
  __syncthreads();
  const long total = 2L*E;
  for (long idx = (long)vb*256 + threadIdx.x; idx < total; idx += 65536L){
    int s = idx >= E;
    int e = (int)(idx - (s ? (long)E : 0));
    int d = (s ? e_xct : e_t)[E + e];
    atomicAdd(&h[s*NBper + (d >> BSH)], 1);
  }
  __syncthreads();
  for (int i = threadIdx.x; i < NB2; i += 256)
    if (h[i]) atomicAdd(&gbcount[i], h[i]);
}

// ---------------- scan bucket counts -> bases, init cursors ----------------
__global__ void k_bscan(const int* __restrict__ gbcount, int* __restrict__ gbase,
                        int* __restrict__ gcursor, int NB2, int total){
  __shared__ int sm[1024];
  const int t = threadIdx.x;
  int v = (t < NB2) ? gbcount[t] : 0;
  sm[t] = v; __syncthreads();
  for (int d = 1; d < 1024; d <<= 1){
    int u = (t >= d) ? sm[t-d] : 0;
    __syncthreads();
    sm[t] += u;
    __syncthreads();
  }
  if (t < NB2){ int ex = sm[t] - v; gbase[t] = ex; gcursor[t] = ex; }
  if (t == 0) gbase[NB2] = total;
}

// ---------------- scatter edges into coarse buckets (packed src|dst<<16) ----------------
#define SCCH 8192
__global__ __launch_bounds__(256) void k_scatter(const int* __restrict__ e_t,
    const int* __restrict__ e_xct, int* __restrict__ gcursor,
    unsigned* __restrict__ gbucket, int E, int NBper){
  __shared__ int cnt[800]; __shared__ int gpos[800]; __shared__ int cur[800];
  const int NB2 = 2*NBper;
  const int t = threadIdx.x;
  for (int i = t; i < NB2; i += 256){ cnt[i] = 0; cur[i] = 0; }
  __syncthreads();
  const long base = (long)blockIdx.x * SCCH;
  const long end  = min(base + SCCH, 2L*E);
  for (long idx = base + t; idx < end; idx += 256){
    int s = idx >= E;
    int e = (int)(idx - (s ? (long)E : 0));
    int d = (s ? e_xct : e_t)[E + e];
    atomicAdd(&cnt[s*NBper + (d >> BSH)], 1);
  }
  __syncthreads();
  for (int i = t; i < NB2; i += 256)
    if (cnt[i]) gpos[i] = atomicAdd(&gcursor[i], cnt[i]);
  __syncthreads();
  for (long idx = base + t; idx < end; idx += 256){
    int s = idx >= E;
    int e = (int)(idx - (s ? (long)E : 0));
    const int* ei = s ? e_xct : e_t;
    int sv = ei[e];
    int d  = ei[E + e];
    int b  = s*NBper + (d >> BSH);
    int pos = atomicAdd(&cur[b], 1);
    gbucket[gpos[b] + pos] = (unsigned)sv | ((unsigned)d << 16);
  }
}

// ---------------- per-bucket: bin by exact destination, write offs + csr ----------------
__global__ __launch_bounds__(256) void k_build(const unsigned* __restrict__ gbucket,
    const int* __restrict__ gbase, int* __restrict__ offs,
    unsigned short* __restrict__ csr, int N, int E, int NBper){
  __shared__ int cnt[128]; __shared__ int pre[128]; __shared__ int cur[128];
  const int b  = blockIdx.x;
  const int s  = b >= NBper;
  const int bb = b - s*NBper;
  const int d0 = bb << BSH;
  const int t  = threadIdx.x;
  if (t < 128) cnt[t] = 0;
  __syncthreads();
  const int g0 = gbase[b], g1 = gbase[b+1];
  for (int j = g0 + t; j < g1; j += 256){
    unsigned en = gbucket[j];
    atomicAdd(&cnt[(en >> 16) & 127], 1);
  }
  __syncthreads();
  int v = (t < 128) ? cnt[t] : 0;
  if (t < 128) pre[t] = v;
  __syncthreads();
  for (int d = 1; d < 128; d <<= 1){
    int u = (t >= d && t < 128) ? pre[t-d] : 0;
    __syncthreads();
    if (t < 128) pre[t] += u;
    __syncthreads();
  }
  if (t < 128){
    int ex = pre[t] - v;
    cur[t] = ex;
    int dd = d0 + t;
    if (dd < N) offs[(size_t)s*(N+1) + dd] = (g0 - s*E) + ex;
  }
  if (t == 128 + 0 && bb == NBper-1) offs[(size_t)s*(N+1) + N] = E;
  __syncthreads();
  for (int j = g0 + t; j < g1; j += 256){
    unsigned en = gbucket[j];
    int d7 = (en >> 16) & 127;
    int pos = atomicAdd(&cur[d7], 1);
    csr[(size_t)g0 + pos] = (unsigned short)(en & 0xFFFFu);
  }
}

// ---------------- gather-aggregate: hA = t + segsum_A(t), hB = t + segsum_B(x) ----------------
__global__ __launch_bounds__(256) void k_gather(const unsigned short* __restrict__ th,
    const unsigned short* __restrict__ xh, const int* __restrict__ offs,
    const unsigned short* __restrict__ csr, unsigned short* hA, unsigned short* hB,
    int N, int E){
  const int w = threadIdx.x >> 6, l = threadIdx.x & 63;
  const long wid = (long)blockIdx.x*4 + w;
  if (wid >= 2L*N) return;
  const int s = wid >= N;
  const int i = (int)(wid - (s ? N : 0));
  const int* off = offs + (size_t)s*(N+1);
  const unsigned short* src = s ? xh : th;
  const unsigned short* cs = csr + (size_t)s*E;
  const int o0 = off[i], o1 = off[i+1];
  const int deg = o1 - o0;
  const int rs = l >> 4;
  const int q  = l & 15;
  float a0=0,a1=0,a2=0,a3=0,a4=0,a5=0,a6=0,a7=0;
  if (deg > 0){
    int ce = cs[o0 + (l < deg ? l : deg-1)];
    for (int base = 0; base < deg; base += 64){
      const int nb = min(64, deg - base);
      const int ce_cur = ce;
      const int nxt = base + 64;
      if (nxt < deg){
        const int rem2 = deg - nxt;
        ce = cs[o0 + nxt + (l < rem2 ? l : rem2-1)];   // prefetch next window
      }
      for (int jj = 0; jj < nb; jj += 16){
        #pragma unroll
        for (int u4 = 0; u4 < 4; ++u4){
          const int idx = jj + u4*4 + rs;
          const int r = __shfl(ce_cur, idx < nb ? idx : nb-1);  // uniform, clamped
          uint4 v = *(const uint4*)(src + (size_t)r*DD + q*8);
          const unsigned m = (idx < nb) ? 0xFFFFFFFFu : 0u;
          v.x &= m; v.y &= m; v.z &= m; v.w &= m;
          a0+=blo(v.x); a1+=bhi(v.x); a2+=blo(v.y); a3+=bhi(v.y);
          a4+=blo(v.z); a5+=bhi(v.z); a6+=blo(v.w); a7+=bhi(v.w);
        }
      }
    }
  }
  a0 += __shfl_xor(a0,16); a1 += __shfl_xor(a1,16);
  a2 += __shfl_xor(a2,16); a3 += __shfl_xor(a3,16);
  a4 += __shfl_xor(a4,16); a5 += __shfl_xor(a5,16);
  a6 += __shfl_xor(a6,16); a7 += __shfl_xor(a7,16);
  a0 += __shfl_xor(a0,32); a1 += __shfl_xor(a1,32);
  a2 += __shfl_xor(a2,32); a3 += __shfl_xor(a3,32);
  a4 += __shfl_xor(a4,32); a5 += __shfl_xor(a5,32);
  a6 += __shfl_xor(a6,32); a7 += __shfl_xor(a7,32);
  if (l < 16){
    uint4 tv = *(const uint4*)(th + (size_t)i*DD + q*8);
    a0+=blo(tv.x); a1+=bhi(tv.x); a2+=blo(tv.y); a3+=bhi(tv.y);
    a4+=blo(tv.z); a5+=bhi(tv.z); a6+=blo(tv.w); a7+=bhi(tv.w);
    uint4 o;
    o.x = pk2(a0,a1); o.y = pk2(a2,a3); o.z = pk2(a4,a5); o.w = pk2(a6,a7);
    *(uint4*)((s ? hB : hA) + (size_t)i*DD + q*8) = o;
  }
}

// ================= fused GEMM-chain machinery =================
// A frag: row = lane&15, k = 8*(lane>>4)+j ; C/D: col = lane&15, row = 4*(lane>>4)+reg
// B operand read from LDS weight tile staged via global_load_lds (linear image,
// pre-swizzled in k_pre; read applies idx ^ ((c0&7)<<3)).

// ---- async weight staging: 8 x global_load_lds(16B) per thread, no VGPRs ----
__device__ __forceinline__ void stage_issue(const unsigned short* __restrict__ Wt,
                                            unsigned short* wlds){
  const int tid = threadIdx.x;
  const int w = tid >> 6, l = tid & 63;
  #pragma unroll
  for (int i = 0; i < 8; ++i){
    const int cbase = i*256 + w*64;           // wave-uniform chunk base
    __builtin_amdgcn_global_load_lds(
      (const __attribute__((address_space(1))) unsigned*)(Wt + (size_t)(cbase + l)*8),
      (__attribute__((address_space(3))) unsigned*)(wlds + (size_t)cbase*8),
      16, 0, 0);
  }
}

// GEMM with A-fragments already in registers
__device__ __forceinline__ void gemm_regA(const bf16x8 a[4], int c0, int swz_g,
    const unsigned short* wlds, f32x4 acc[8]){
  #pragma unroll
  for (int kb = 0; kb < 4; ++kb){
    const int co = (kb*32) ^ swz_g;           // swz_g = (g*8) ^ ((c0&7)<<3); kb*32 has no bits 3-4
    #pragma unroll
    for (int cb = 0; cb < 8; ++cb){
      bf16x8 b = *(const bf16x8*)(wlds + (cb*16 + c0)*DD + ((kb*32 + (swz_g & ~32)) ^ (swz_g & 32)));
      // NOTE: simplified below — see gemm body; this line unused
      (void)b;
    }
  }
}

// real helpers (keep it simple: full index XOR each time; compiler folds constants)
__device__ __forceinline__ void gemm_reg(const bf16x8 a[4], int c0, int g, int swz,
    const unsigned short* wlds, f32x4 acc[8]){
  #pragma unroll
  for (int kb = 0; kb < 4; ++kb){
    const int co = (kb*32 + g*8) ^ swz;
    #pragma unroll
    for (int cb = 0; cb < 8; ++cb){
      bf16x8 b = *(const bf16x8*)(wlds + (cb*16 + c0)*DD + co);
      acc[cb] = __builtin_amdgcn_mfma_f32_16x16x32_bf16(a[kb], b, acc[cb], 0, 0, 0);
    }
  }
}

__device__ __forceinline__ void gemm_lds(const unsigned short* lds,
    int w, int c0, int g, int swz, const unsigned short* wlds, f32x4 acc[8]){
  const unsigned short* ap = lds + (w*16 + c0)*LSTR + g*8;
  #pragma unroll
  for (int kb = 0; kb < 4; ++kb){
    bf16x8 a = *(const bf16x8*)(ap + kb*32);
    const int co = (kb*32 + g*8) ^ swz;
    #pragma unroll
    for (int cb = 0; cb < 8; ++cb){
      bf16x8 b = *(const bf16x8*)(wlds + (cb*16 + c0)*DD + co);
      acc[cb] = __builtin_amdgcn_mfma_f32_16x16x32_bf16(a, b, acc[cb], 0, 0, 0);
    }
  }
}

// ---------- t-branch chain (5 GEMMs) as device fn ----------
__device__ __forceinline__ void chainT_body(unsigned short* lds, unsigned short* wlds,
    int bid,
    const unsigned short* __restrict__ hA, const unsigned short* __restrict__ hB,
    const unsigned short* __restrict__ W1a, const float* __restrict__ b1a,
    const unsigned short* __restrict__ W2a, const float* __restrict__ b2a,
    const unsigned short* __restrict__ W1b, const float* __restrict__ b1b,
    const unsigned short* __restrict__ W2b, const float* __restrict__ b2b,
    const unsigned short* __restrict__ Wo,  const float* __restrict__ bo,
    const unsigned short* __restrict__ th,
    const float* __restrict__ lng, const float* __restrict__ lnb,
    float* __restrict__ outT, int N)
{
  const int tid = threadIdx.x;
  const int w = tid >> 6, l = tid & 63;
  const int g = l >> 4, c0 = l & 15;
  const int swz = (c0 & 7) << 3;
  const int rbase = bid*64 + w*16;

  // ---- block-start prefetch: A-fragments of both branches + th residual ----
  int arow = rbase + c0; if (arow > N-1) arow = N-1;
  const unsigned short* apA = hA + (size_t)arow*DD + g*8;
  const unsigned short* apB = hB + (size_t)arow*DD + g*8;
  bf16x8 aA[4], aB[4];
  #pragma unroll
  for (int kb = 0; kb < 4; ++kb){
    aA[kb] = *(const bf16x8*)(apA + kb*32);
    aB[kb] = *(const bf16x8*)(apB + kb*32);
  }
  unsigned short thr_[8][4];
  #pragma unroll
  for (int cb = 0; cb < 8; ++cb){
    #pragma unroll
    for (int r = 0; r < 4; ++r){
      int orow = rbase + 4*g + r;
      int rc = orow > N-1 ? N-1 : orow;
      thr_[cb][r] = th[(size_t)rc*DD + cb*16 + c0];
    }
  }
  stage_issue(W1a, wlds);
  __syncthreads();                    // W1a ready (+ prefetches landed)

  f32x4 acc[8];

  // ---- GEMM 1: hA @ W1a ----
  #pragma unroll
  for (int cb = 0; cb < 8; ++cb) acc[cb] = 0.f;
  gemm_reg(aA, c0, g, swz, wlds, acc);
  __syncthreads();                    // all waves done reading W1a
  stage_issue(W2a, wlds);
  #pragma unroll
  for (int cb = 0; cb < 8; ++cb){
    float bv = b1a[cb*16 + c0];
    #pragma unroll
    for (int r = 0; r < 4; ++r)
      lds[(w*16 + 4*g + r)*LSTR + cb*16 + c0] = f2b(fmaxf(acc[cb][r] + bv, 0.f));
  }
  __syncthreads();                    // W2a ready, h1 written

  // ---- GEMM 2: h1 @ W2a -> pAv ----
  #pragma unroll
  for (int cb = 0; cb < 8; ++cb) acc[cb] = 0.f;
  gemm_lds(lds, w, c0, g, swz, wlds, acc);
  float pAv[8][4];
  #pragma unroll
  for (int cb = 0; cb < 8; ++cb){
    float bv = b2a[cb*16 + c0];
    #pragma unroll
    for (int r = 0; r < 4; ++r) pAv[cb][r] = acc[cb][r] + bv;
  }
  __syncthreads();                    // all waves done reading W2a
  stage_issue(W1b, wlds);
  __syncthreads();                    // W1b ready

  // ---- GEMM 3: hB @ W1b ----
  #pragma unroll
  for (int cb = 0; cb < 8; ++cb) acc[cb] = 0.f;
  gemm_reg(aB, c0, g, swz, wlds, acc);
  __syncthreads();                    // done reading W1b
  stage_issue(W2b, wlds);
  #pragma unroll
  for (int cb = 0; cb < 8; ++cb){
    float bv = b1b[cb*16 + c0];
    #pragma unroll
    for (int r = 0; r < 4; ++r)
      lds[(w*16 + 4*g + r)*LSTR + cb*16 + c0] = f2b(fmaxf(acc[cb][r] + bv, 0.f));
  }
  __syncthreads();                    // W2b ready, h3 written

  // ---- GEMM 4: h3 @ W2b -> t2 ----
  #pragma unroll
  for (int cb = 0; cb < 8; ++cb) acc[cb] = 0.f;
  gemm_lds(lds, w, c0, g, swz, wlds, acc);
  __syncthreads();                    // done reading W2b
  stage_issue(Wo, wlds);

  float t2f[8][4];
  #pragma unroll
  for (int cb = 0; cb < 8; ++cb){
    float bv = b2b[cb*16 + c0];
    #pragma unroll
    for (int r = 0; r < 4; ++r){
      float v = fmaxf(acc[cb][r] + bv + b2f(thr_[cb][r]) + pAv[cb][r], 0.f);
      t2f[cb][r] = v;
      lds[(w*16 + 4*g + r)*LSTR + cb*16 + c0] = f2b(v);
    }
  }
  __syncthreads();                    // Wo ready, t2 written

  // ---- GEMM 5: t2 @ Wo + LN + residual ----
  #pragma unroll
  for (int cb = 0; cb < 8; ++cb) acc[cb] = 0.f;
  gemm_lds(lds, w, c0, g, swz, wlds, acc);

  float u[8][4];
  float sm_[4] = {0,0,0,0}, sq_[4] = {0,0,0,0};
  #pragma unroll
  for (int cb = 0; cb < 8; ++cb){
    float bv = bo[cb*16 + c0];
    #pragma unroll
    for (int r = 0; r < 4; ++r){
      float v = fmaxf(acc[cb][r] + bv, 0.f);
      u[cb][r] = v;
      sm_[r] += v; sq_[r] += v*v;
    }
  }
  #pragma unroll
  for (int m = 1; m < 16; m <<= 1){
    #pragma unroll
    for (int r = 0; r < 4; ++r){
      sm_[r] += __shfl_xor(sm_[r], m, 64);
      sq_[r] += __shfl_xor(sq_[r], m, 64);
    }
  }
  float mean[4], rstd[4];
  #pragma unroll
  for (int r = 0; r < 4; ++r){
    mean[r] = sm_[r] * (1.0f/DD);
    float var = sq_[r] * (1.0f/DD) - mean[r]*mean[r];
    rstd[r] = rsqrtf(var + 1e-5f);
  }
  #pragma unroll
  for (int cb = 0; cb < 8; ++cb){
    float gv = lng[cb*16 + c0], bv2 = lnb[cb*16 + c0];
    #pragma unroll
    for (int r = 0; r < 4; ++r){
      int orow = rbase + 4*g + r;
      if (orow < N){
        size_t oi = (size_t)orow*DD + cb*16 + c0;
        outT[oi] = (u[cb][r] - mean[r]) * rstd[r] * gv + bv2 + t2f[cb][r];
      }
    }
  }
}

// ---------- fc_x MLP as device fn ----------
__device__ __forceinline__ void mlp2_body(unsigned short* lds, unsigned short* wlds,
    int bid,
    const unsigned short* __restrict__ X,
    const unsigned short* __restrict__ W1, const float* __restrict__ b1,
    const unsigned short* __restrict__ W2, const float* __restrict__ b2,
    const unsigned short* __restrict__ resh, float* __restrict__ outF, int N)
{
  const int tid = threadIdx.x;
  const int w = tid >> 6, l = tid & 63;
  const int g = l >> 4, c0 = l & 15;
  const int swz = (c0 & 7) << 3;
  const int rbase = bid*64 + w*16;

  // prefetch A-frags + residual
  int arow = rbase + c0; if (arow > N-1) arow = N-1;
  const unsigned short* apX = X + (size_t)arow*DD + g*8;
  bf16x8 aX[4];
  #pragma unroll
  for (int kb = 0; kb < 4; ++kb) aX[kb] = *(const bf16x8*)(apX + kb*32);
  unsigned short rs_[8][4];
  #pragma unroll
  for (int cb = 0; cb < 8; ++cb){
    #pragma unroll
    for (int r = 0; r < 4; ++r){
      int orow = rbase + 4*g + r;
      int rc = orow > N-1 ? N-1 : orow;
      rs_[cb][r] = resh[(size_t)rc*DD + cb*16 + c0];
    }
  }
  stage_issue(W1, wlds);
  __syncthreads();

  f32x4 acc[8];
  // ---- GEMM 1 ----
  #pragma unroll
  for (int cb = 0; cb < 8; ++cb) acc[cb] = 0.f;
  gemm_reg(aX, c0, g, swz, wlds, acc);
  __syncthreads();                    // done reading W1
  stage_issue(W2, wlds);
  #pragma unroll
  for (int cb = 0; cb < 8; ++cb){
    float bv = b1[cb*16 + c0];
    #pragma unroll
    for (int r = 0; r < 4; ++r)
      lds[(w*16 + 4*g + r)*LSTR + cb*16 + c0] = f2b(fmaxf(acc[cb][r] + bv, 0.f));
  }
  __syncthreads();                    // W2 ready, h written

  // ---- GEMM 2 ----
  #pragma unroll
  for (int cb = 0; cb < 8; ++cb) acc[cb] = 0.f;
  gemm_lds(lds, w, c0, g, swz, wlds, acc);

  #pragma unroll
  for (int cb = 0; cb < 8; ++cb){
    float bv = b2[cb*16 + c0];
    #pragma unroll
    for (int r = 0; r < 4; ++r){
      int orow = rbase + 4*g + r;
      if (orow < N){
        size_t oi = (size_t)orow*DD + cb*16 + c0;
        outF[oi] = acc[cb][r] + bv + b2f(rs_[cb][r]);
      }
    }
  }
}

// ---------- fused tail: [0,gg) chainT ; [gg,2gg) fc_x ----------
__global__ __launch_bounds__(256, 3) void k_tail(
    const unsigned short* __restrict__ hA, const unsigned short* __restrict__ hB,
    const unsigned short* __restrict__ xh, const unsigned short* __restrict__ th,
    const unsigned short* __restrict__ wt,
    const float* __restrict__ b1a, const float* __restrict__ b2a,
    const float* __restrict__ b1b, const float* __restrict__ b2b,
    const float* __restrict__ bo,  const float* __restrict__ lng,
    const float* __restrict__ lnb, const float* __restrict__ bf1,
    const float* __restrict__ bf2,
    float* __restrict__ outX, float* __restrict__ outT, int N, int gg)
{
  __shared__ unsigned short lds[64*LSTR];     // 17408 B  h/intermediate tiles (wave-private rows)
  __shared__ unsigned short wlds[DD*DD];      // 32768 B  linear weight image (pre-swizzled)
  const unsigned short* W1a = wt + 0*DD*DD;
  const unsigned short* W2a = wt + 1*DD*DD;
  const unsigned short* W1b = wt + 2*DD*DD;
  const unsigned short* W2b = wt + 3*DD*DD;
  const unsigned short* Wo  = wt + 4*DD*DD;
  const unsigned short* Wf1 = wt + 5*DD*DD;
  const unsigned short* Wf2 = wt + 6*DD*DD;
  if (blockIdx.x < (unsigned)gg){
    chainT_body(lds, wlds, blockIdx.x, hA, hB, W1a, b1a, W2a, b2a, W1b, b1b, W2b, b2b,
                Wo, bo, th, lng, lnb, outT, N);
  } else {
    mlp2_body(lds, wlds, blockIdx.x - gg, xh, Wf1, bf1, Wf2, bf2, xh, outX, N);
  }
}

extern "C" void kernel_launch(void* const* d_in, const int* in_sizes, int n_in,
                              void* d_out, int out_size, void* d_ws, size_t ws_size,
                              hipStream_t stream) {
  const float* x     = (const float*)d_in[0];
  const float* t     = (const float*)d_in[1];
  const int*   e_t   = (const int*)d_in[2];
  const int*   e_xct = (const int*)d_in[3];
  const float* b1a = (const float*)d_in[5];
  const float* b2a = (const float*)d_in[7];
  const float* b1b = (const float*)d_in[9];
  const float* b2b = (const float*)d_in[11];
  const float* bo  = (const float*)d_in[13];
  const float* lng = (const float*)d_in[14];
  const float* lnb = (const float*)d_in[15];
  const float* bf1 = (const float*)d_in[17];
  const float* bf2 = (const float*)d_in[19];

  const int N = in_sizes[0] / DD;     // 50000
  const int E = in_sizes[2] / 2;      // 1600000
  const int NBper = (N + 127) >> BSH; // 391
  const int NB2 = 2*NBper;            // 782

  // ---- workspace carve ----
  char* p = (char*)d_ws;
  auto carve = [&](size_t b)->char*{ char* r = p; p += (b + 255) & ~(size_t)255; return r; };
  size_t nd2 = (size_t)N*DD*2, nd4 = (size_t)N*DD*4;
  unsigned short* xh = (unsigned short*)carve(nd2);
  unsigned short* th = (unsigned short*)carve(nd2);
  unsigned short* hA = (unsigned short*)carve(nd2);
  unsigned short* hB = (unsigned short*)carve(nd2);
  float*          pA = (float*)carve(nd4);            // gbucket alias only
  unsigned short* wt = (unsigned short*)carve((size_t)7*DD*DD*2);
  int* gbcount = (int*)carve((size_t)NB2*4);
  int* gbase   = (int*)carve((size_t)(NB2+1)*4);
  int* gcursor = (int*)carve((size_t)NB2*4);
  int* offs    = (int*)carve((size_t)2*(N+1)*4);
  unsigned short* csr = (unsigned short*)carve((size_t)2*E*2);
  unsigned* gbucket = (unsigned*)pA;                  // 2E*4 = 12.8MB <= nd4 (25.6MB)

  float* outX = (float*)d_out;
  float* outT = outX + (size_t)N*DD;

  hipMemsetAsync(gbcount, 0, (size_t)NB2*4, stream);

  WP wp;
  wp.w[0] = (const float*)d_in[4];  wp.w[1] = (const float*)d_in[6];
  wp.w[2] = (const float*)d_in[8];  wp.w[3] = (const float*)d_in[10];
  wp.w[4] = (const float*)d_in[12]; wp.w[5] = (const float*)d_in[16];
  wp.w[6] = (const float*)d_in[18];

  const int M4 = N*DD/4;
  const int ncv = (2*M4 + 255)/256;
  k_pre<<<ncv + 7 + 256, 256, 0, stream>>>(x, t, (unsigned*)xh, (unsigned*)th, M4,
                                           wp, wt, e_t, e_xct, gbcount, E, NBper, ncv);
  k_bscan<<<1, 1024, 0, stream>>>(gbcount, gbase, gcursor, NB2, 2*E);
  const int nsc = (int)((2L*E + SCCH-1) / SCCH);
  k_scatter<<<nsc, 256, 0, stream>>>(e_t, e_xct, gcursor, gbucket, E, NBper);
  k_build<<<NB2, 256, 0, stream>>>(gbucket, gbase, offs, csr, N, E, NBper);
  k_gather<<<(2*N + 3)/4, 256, 0, stream>>>(th, xh, offs, csr, hA, hB, N, E);

  const int gg = (N + 63)/64;
  k_tail<<<2*gg, 256, 0, stream>>>(hA, hB, xh, th, wt, b1a, b2a, b1b, b2b, bo,
                                   lng, lnb, bf1, bf2, outX, outT, N, gg);
}

// Round 3
// 232.784 us; speedup vs baseline: 1.3223x; 1.0021x over previous
//
#include <hip/hip_runtime.h>

#define DD 128
#define BSH 7
#define LSTR 136   // h-tile LDS row stride in bf16 elems: 272B -> 2-way bank alias max (free)

typedef __attribute__((ext_vector_type(8))) short bf16x8;
typedef __attribute__((ext_vector_type(4))) float f32x4;
typedef __attribute__((ext_vector_type(2))) float f32x2;

__device__ __forceinline__ unsigned short f2b(float f){
  unsigned u = __builtin_bit_cast(unsigned, f);
  u += 0x7FFFu + ((u >> 16) & 1u);            // round-to-nearest-even
  return (unsigned short)(u >> 16);
}
__device__ __forceinline__ float blo(unsigned u){ return __builtin_bit_cast(float, u << 16); }
__device__ __forceinline__ float bhi(unsigned u){ return __builtin_bit_cast(float, u & 0xFFFF0000u); }
__device__ __forceinline__ float b2f(unsigned short h){ return __builtin_bit_cast(float, ((unsigned)h) << 16); }
__device__ __forceinline__ unsigned pk2(float a, float b){
  return (unsigned)f2b(a) | ((unsigned)f2b(b) << 16);
}

// ---------------- fused pre: convert x,t -> bf16 | weight transpose (XOR-swizzled) | zero-row | bucket hist ----------------
// Weight image: W^T row-major 128x128 bf16, element (row=c, col=k) stored at
// index (c*128 + k) ^ ((c&7)<<3). global_load_lds copies linearly; ds_read applies same XOR.
struct WP { const float* w[7]; };
__global__ __launch_bounds__(256) void k_pre(const float* __restrict__ x,
    const float* __restrict__ t, unsigned* __restrict__ xh, unsigned* __restrict__ th,
    int M, WP p, unsigned short* __restrict__ wt,
    const int* __restrict__ e_t, const int* __restrict__ e_xct,
    int* __restrict__ gbcount, int E, int NBper, int ncv, int N){
  const int bid = blockIdx.x;
  if (bid < ncv){
    int tid = bid*256 + threadIdx.x;
    if (tid < M){
      float4 v = ((const float4*)x)[tid];
      ((uint2*)xh)[tid] = make_uint2(pk2(v.x, v.y), pk2(v.z, v.w));
    } else if (tid < 2*M){
      int k = tid - M;
      float4 v = ((const float4*)t)[k];
      ((uint2*)th)[k] = make_uint2(pk2(v.x, v.y), pk2(v.z, v.w));
    }
    return;
  }
  if (bid < ncv + 7){
    const float* W = p.w[bid - ncv];
    unsigned short* dst = wt + (size_t)(bid - ncv)*DD*DD;
    for (int e = threadIdx.x; e < DD*DD; e += 256){
      int k = e >> 7, c = e & 127;
      dst[(c*DD + k) ^ ((c & 7) << 3)] = f2b(W[e]);
    }
    return;
  }
  if (bid == ncv + 7){
    // zero row N of xh and th (ZROW for the gather)
    const int tid = threadIdx.x;
    uint4 z; z.x = 0; z.y = 0; z.z = 0; z.w = 0;
    if (tid < 16)      ((uint4*)(xh + (size_t)N*(DD/2)))[tid]      = z;
    else if (tid < 32) ((uint4*)(th + (size_t)N*(DD/2)))[tid - 16] = z;
    return;
  }
  // bucket histogram (256 virtual blocks)
  __shared__ int h[800];
  const int vb = bid - ncv - 8;
  const int NB2 = 2*NBper;
  for (int i = threadIdx.x; i < NB2; i += 256) h[i] = 0;
  __syncthreads();
  const long total = 2L*E;
  for (long idx = (long)vb*256 + threadIdx.x; idx < total; idx += 65536L){
    int s = idx >= E;
    int e = (int)(idx - (s ? (long)E : 0));
    int d = (s ? e_xct : e_t)[E + e];
    atomicAdd(&h[s*NBper + (d >> BSH)], 1);
  }
  __syncthreads();
  for (int i = threadIdx.x; i < NB2; i += 256)
    if (h[i]) atomicAdd(&gbcount[i], h[i]);
}

// ---------------- scan bucket counts -> bases, init cursors ----------------
__global__ void k_bscan(const int* __restrict__ gbcount, int* __restrict__ gbase,
                        int* __restrict__ gcursor, int NB2, int total){
  __shared__ int sm[1024];
  const int t = threadIdx.x;
  int v = (t < NB2) ? gbcount[t] : 0;
  sm[t] = v; __syncthreads();
  for (int d = 1; d < 1024; d <<= 1){
    int u = (t >= d) ? sm[t-d] : 0;
    __syncthreads();
    sm[t] += u;
    __syncthreads();
  }
  if (t < NB2){ int ex = sm[t] - v; gbase[t] = ex; gcursor[t] = ex; }
  if (t == 0) gbase[NB2] = total;
}

// ---------------- scatter edges into coarse buckets (packed src|dst<<16) ----------------
#define SCCH 8192
__global__ __launch_bounds__(256) void k_scatter(const int* __restrict__ e_t,
    const int* __restrict__ e_xct, int* __restrict__ gcursor,
    unsigned* __restrict__ gbucket, int E, int NBper){
  __shared__ int cnt[800]; __shared__ int gpos[800]; __shared__ int cur[800];
  const int NB2 = 2*NBper;
  const int t = threadIdx.x;
  for (int i = t; i < NB2; i += 256){ cnt[i] = 0; cur[i] = 0; }
  __syncthreads();
  const long base = (long)blockIdx.x * SCCH;
  const long end  = min(base + SCCH, 2L*E);
  for (long idx = base + t; idx < end; idx += 256){
    int s = idx >= E;
    int e = (int)(idx - (s ? (long)E : 0));
    int d = (s ? e_xct : e_t)[E + e];
    atomicAdd(&cnt[s*NBper + (d >> BSH)], 1);
  }
  __syncthreads();
  for (int i = t; i < NB2; i += 256)
    if (cnt[i]) gpos[i] = atomicAdd(&gcursor[i], cnt[i]);
  __syncthreads();
  for (long idx = base + t; idx < end; idx += 256){
    int s = idx >= E;
    int e = (int)(idx - (s ? (long)E : 0));
    const int* ei = s ? e_xct : e_t;
    int sv = ei[e];
    int d  = ei[E + e];
    int b  = s*NBper + (d >> BSH);
    int pos = atomicAdd(&cur[b], 1);
    gbucket[gpos[b] + pos] = (unsigned)sv | ((unsigned)d << 16);
  }
}

// ---------------- per-bucket: bin by exact destination, write offs + csr ----------------
__global__ __launch_bounds__(256) void k_build(const unsigned* __restrict__ gbucket,
    const int* __restrict__ gbase, int* __restrict__ offs,
    unsigned short* __restrict__ csr, int N, int E, int NBper){
  __shared__ int cnt[128]; __shared__ int pre[128]; __shared__ int cur[128];
  const int b  = blockIdx.x;
  const int s  = b >= NBper;
  const int bb = b - s*NBper;
  const int d0 = bb << BSH;
  const int t  = threadIdx.x;
  if (t < 128) cnt[t] = 0;
  __syncthreads();
  const int g0 = gbase[b], g1 = gbase[b+1];
  for (int j = g0 + t; j < g1; j += 256){
    unsigned en = gbucket[j];
    atomicAdd(&cnt[(en >> 16) & 127], 1);
  }
  __syncthreads();
  int v = (t < 128) ? cnt[t] : 0;
  if (t < 128) pre[t] = v;
  __syncthreads();
  for (int d = 1; d < 128; d <<= 1){
    int u = (t >= d && t < 128) ? pre[t-d] : 0;
    __syncthreads();
    if (t < 128) pre[t] += u;
    __syncthreads();
  }
  if (t < 128){
    int ex = pre[t] - v;
    cur[t] = ex;
    int dd = d0 + t;
    if (dd < N) offs[(size_t)s*(N+1) + dd] = (g0 - s*E) + ex;
  }
  if (t == 128 + 0 && bb == NBper-1) offs[(size_t)s*(N+1) + N] = E;
  __syncthreads();
  for (int j = g0 + t; j < g1; j += 256){
    unsigned en = gbucket[j];
    int d7 = (en >> 16) & 127;
    int pos = atomicAdd(&cur[d7], 1);
    csr[(size_t)g0 + pos] = (unsigned short)(en & 0xFFFFu);
  }
}

// ---------------- gather-aggregate: hA = t + segsum_A(t), hB = t + segsum_B(x) ----------------
// wave per destination node; 16-lane group per neighbor row, 16B/lane.
// Invalid edge slots redirect the ROW INDEX to the zero row (ZROW = N) via one
// cndmask -- no data masking. Accumulate as float2 pairs (v_pk_add_f32).
__global__ __launch_bounds__(256) void k_gather(const unsigned short* __restrict__ th,
    const unsigned short* __restrict__ xh, const int* __restrict__ offs,
    const unsigned short* __restrict__ csr, unsigned short* hA, unsigned short* hB,
    int N, int E){
  const int w = threadIdx.x >> 6, l = threadIdx.x & 63;
  const long wid = (long)blockIdx.x*4 + w;
  if (wid >= 2L*N) return;
  const int s = wid >= N;
  const int i = (int)(wid - (s ? N : 0));
  const int* off = offs + (size_t)s*(N+1);
  const unsigned short* src = s ? xh : th;
  const unsigned short* cs = csr + (size_t)s*E;
  const int o0 = off[i], o1 = off[i+1];
  const int deg = o1 - o0;
  const int rs = l >> 4;
  const int q  = l & 15;
  const unsigned short* srcq = src + q*8;
  f32x2 A0 = 0.f, A1 = 0.f, A2 = 0.f, A3 = 0.f;
  if (deg > 0){
    int ce = cs[o0 + (l < deg ? l : deg-1)];
    for (int base = 0; base < deg; base += 64){
      const int nb = min(64, deg - base);
      const int ce_cur = ce;
      const int nxt = base + 64;
      if (nxt < deg){
        const int rem2 = deg - nxt;
        ce = cs[o0 + nxt + (l < rem2 ? l : rem2-1)];   // prefetch next window
      }
      for (int jj = 0; jj < nb; jj += 16){
        #pragma unroll
        for (int u4 = 0; u4 < 4; ++u4){
          const int idx = jj + u4*4 + rs;              // < 64 always
          int r = __shfl(ce_cur, idx);                 // uniform per 16-lane group
          r = (idx < nb) ? r : N;                      // invalid -> zero row
          uint4 v = *(const uint4*)(srcq + (size_t)r*DD);
          A0 += (f32x2){blo(v.x), bhi(v.x)};
          A1 += (f32x2){blo(v.y), bhi(v.y)};
          A2 += (f32x2){blo(v.z), bhi(v.z)};
          A3 += (f32x2){blo(v.w), bhi(v.w)};
        }
      }
    }
  }
  #pragma unroll
  for (int m = 16; m <= 32; m <<= 1){
    A0.x += __shfl_xor(A0.x, m); A0.y += __shfl_xor(A0.y, m);
    A1.x += __shfl_xor(A1.x, m); A1.y += __shfl_xor(A1.y, m);
    A2.x += __shfl_xor(A2.x, m); A2.y += __shfl_xor(A2.y, m);
    A3.x += __shfl_xor(A3.x, m); A3.y += __shfl_xor(A3.y, m);
  }
  if (l < 16){
    uint4 tv = *(const uint4*)(th + (size_t)i*DD + q*8);
    A0 += (f32x2){blo(tv.x), bhi(tv.x)};
    A1 += (f32x2){blo(tv.y), bhi(tv.y)};
    A2 += (f32x2){blo(tv.z), bhi(tv.z)};
    A3 += (f32x2){blo(tv.w), bhi(tv.w)};
    uint4 o;
    o.x = pk2(A0.x, A0.y); o.y = pk2(A1.x, A1.y);
    o.z = pk2(A2.x, A2.y); o.w = pk2(A3.x, A3.y);
    *(uint4*)((s ? hB : hA) + (size_t)i*DD + q*8) = o;
  }
}

// ================= fused GEMM-chain machinery =================
// A frag: row = lane&15, k = 8*(lane>>4)+j ; C/D: col = lane&15, row = 4*(lane>>4)+reg
// B operand read from LDS weight tile staged via global_load_lds (linear image,
// pre-swizzled in k_pre; read applies idx ^ ((c0&7)<<3)).

// ---- async weight staging: 8 x global_load_lds(16B) per thread, no VGPRs ----
__device__ __forceinline__ void stage_issue(const unsigned short* __restrict__ Wt,
                                            unsigned short* wlds){
  const int tid = threadIdx.x;
  const int w = tid >> 6, l = tid & 63;
  #pragma unroll
  for (int i = 0; i < 8; ++i){
    const int cbase = i*256 + w*64;           // wave-uniform chunk base
    __builtin_amdgcn_global_load_lds(
      (const __attribute__((address_space(1))) unsigned*)(Wt + (size_t)(cbase + l)*8),
      (__attribute__((address_space(3))) unsigned*)(wlds + (size_t)cbase*8),
      16, 0, 0);
  }
}

__device__ __forceinline__ void gemm_reg(const bf16x8 a[4], int c0, int g, int swz,
    const unsigned short* wlds, f32x4 acc[8]){
  #pragma unroll
  for (int kb = 0; kb < 4; ++kb){
    const int co = (kb*32 + g*8) ^ swz;
    #pragma unroll
    for (int cb = 0; cb < 8; ++cb){
      bf16x8 b = *(const bf16x8*)(wlds + (cb*16 + c0)*DD + co);
      acc[cb] = __builtin_amdgcn_mfma_f32_16x16x32_bf16(a[kb], b, acc[cb], 0, 0, 0);
    }
  }
}

__device__ __forceinline__ void gemm_lds(const unsigned short* lds,
    int w, int c0, int g, int swz, const unsigned short* wlds, f32x4 acc[8]){
  const unsigned short* ap = lds + (w*16 + c0)*LSTR + g*8;
  #pragma unroll
  for (int kb = 0; kb < 4; ++kb){
    bf16x8 a = *(const bf16x8*)(ap + kb*32);
    const int co = (kb*32 + g*8) ^ swz;
    #pragma unroll
    for (int cb = 0; cb < 8; ++cb){
      bf16x8 b = *(const bf16x8*)(wlds + (cb*16 + c0)*DD + co);
      acc[cb] = __builtin_amdgcn_mfma_f32_16x16x32_bf16(a, b, acc[cb], 0, 0, 0);
    }
  }
}

// ---------- t-branch chain (5 GEMMs) as device fn ----------
__device__ __forceinline__ void chainT_body(unsigned short* lds, unsigned short* wlds,
    int bid,
    const unsigned short* __restrict__ hA, const unsigned short* __restrict__ hB,
    const unsigned short* __restrict__ W1a, const float* __restrict__ b1a,
    const unsigned short* __restrict__ W2a, const float* __restrict__ b2a,
    const unsigned short* __restrict__ W1b, const float* __restrict__ b1b,
    const unsigned short* __restrict__ W2b, const float* __restrict__ b2b,
    const unsigned short* __restrict__ Wo,  const float* __restrict__ bo,
    const unsigned short* __restrict__ th,
    const float* __restrict__ lng, const float* __restrict__ lnb,
    float* __restrict__ outT, int N)
{
  const int tid = threadIdx.x;
  const int w = tid >> 6, l = tid & 63;
  const int g = l >> 4, c0 = l & 15;
  const int swz = (c0 & 7) << 3;
  const int rbase = bid*64 + w*16;

  // ---- block-start prefetch: A-fragments of both branches + th residual ----
  int arow = rbase + c0; if (arow > N-1) arow = N-1;
  const unsigned short* apA = hA + (size_t)arow*DD + g*8;
  const unsigned short* apB = hB + (size_t)arow*DD + g*8;
  bf16x8 aA[4], aB[4];
  #pragma unroll
  for (int kb = 0; kb < 4; ++kb){
    aA[kb] = *(const bf16x8*)(apA + kb*32);
    aB[kb] = *(const bf16x8*)(apB + kb*32);
  }
  unsigned short thr_[8][4];
  #pragma unroll
  for (int cb = 0; cb < 8; ++cb){
    #pragma unroll
    for (int r = 0; r < 4; ++r){
      int orow = rbase + 4*g + r;
      int rc = orow > N-1 ? N-1 : orow;
      thr_[cb][r] = th[(size_t)rc*DD + cb*16 + c0];
    }
  }
  stage_issue(W1a, wlds);
  __syncthreads();                    // W1a ready (+ prefetches landed)

  f32x4 acc[8];

  // ---- GEMM 1: hA @ W1a ----
  #pragma unroll
  for (int cb = 0; cb < 8; ++cb) acc[cb] = 0.f;
  gemm_reg(aA, c0, g, swz, wlds, acc);
  __syncthreads();                    // all waves done reading W1a
  stage_issue(W2a, wlds);
  #pragma unroll
  for (int cb = 0; cb < 8; ++cb){
    float bv = b1a[cb*16 + c0];
    #pragma unroll
    for (int r = 0; r < 4; ++r)
      lds[(w*16 + 4*g + r)*LSTR + cb*16 + c0] = f2b(fmaxf(acc[cb][r] + bv, 0.f));
  }
  __syncthreads();                    // W2a ready, h1 written

  // ---- GEMM 2: h1 @ W2a -> pAv ----
  #pragma unroll
  for (int cb = 0; cb < 8; ++cb) acc[cb] = 0.f;
  gemm_lds(lds, w, c0, g, swz, wlds, acc);
  float pAv[8][4];
  #pragma unroll
  for (int cb = 0; cb < 8; ++cb){
    float bv = b2a[cb*16 + c0];
    #pragma unroll
    for (int r = 0; r < 4; ++r) pAv[cb][r] = acc[cb][r] + bv;
  }
  __syncthreads();                    // all waves done reading W2a
  stage_issue(W1b, wlds);
  __syncthreads();                    // W1b ready

  // ---- GEMM 3: hB @ W1b ----
  #pragma unroll
  for (int cb = 0; cb < 8; ++cb) acc[cb] = 0.f;
  gemm_reg(aB, c0, g, swz, wlds, acc);
  __syncthreads();                    // done reading W1b
  stage_issue(W2b, wlds);
  #pragma unroll
  for (int cb = 0; cb < 8; ++cb){
    float bv = b1b[cb*16 + c0];
    #pragma unroll
    for (int r = 0; r < 4; ++r)
      lds[(w*16 + 4*g + r)*LSTR + cb*16 + c0] = f2b(fmaxf(acc[cb][r] + bv, 0.f));
  }
  __syncthreads();                    // W2b ready, h3 written

  // ---- GEMM 4: h3 @ W2b -> t2 ----
  #pragma unroll
  for (int cb = 0; cb < 8; ++cb) acc[cb] = 0.f;
  gemm_lds(lds, w, c0, g, swz, wlds, acc);
  __syncthreads();                    // done reading W2b
  stage_issue(Wo, wlds);

  float t2f[8][4];
  #pragma unroll
  for (int cb = 0; cb < 8; ++cb){
    float bv = b2b[cb*16 + c0];
    #pragma unroll
    for (int r = 0; r < 4; ++r){
      float v = fmaxf(acc[cb][r] + bv + b2f(thr_[cb][r]) + pAv[cb][r], 0.f);
      t2f[cb][r] = v;
      lds[(w*16 + 4*g + r)*LSTR + cb*16 + c0] = f2b(v);
    }
  }
  __syncthreads();                    // Wo ready, t2 written

  // ---- GEMM 5: t2 @ Wo + LN + residual ----
  #pragma unroll
  for (int cb = 0; cb < 8; ++cb) acc[cb] = 0.f;
  gemm_lds(lds, w, c0, g, swz, wlds, acc);

  float u[8][4];
  float sm_[4] = {0,0,0,0}, sq_[4] = {0,0,0,0};
  #pragma unroll
  for (int cb = 0; cb < 8; ++cb){
    float bv = bo[cb*16 + c0];
    #pragma unroll
    for (int r = 0; r < 4; ++r){
      float v = fmaxf(acc[cb][r] + bv, 0.f);
      u[cb][r] = v;
      sm_[r] += v; sq_[r] += v*v;
    }
  }
  #pragma unroll
  for (int m = 1; m < 16; m <<= 1){
    #pragma unroll
    for (int r = 0; r < 4; ++r){
      sm_[r] += __shfl_xor(sm_[r], m, 64);
      sq_[r] += __shfl_xor(sq_[r], m, 64);
    }
  }
  float mean[4], rstd[4];
  #pragma unroll
  for (int r = 0; r < 4; ++r){
    mean[r] = sm_[r] * (1.0f/DD);
    float var = sq_[r] * (1.0f/DD) - mean[r]*mean[r];
    rstd[r] = rsqrtf(var + 1e-5f);
  }
  #pragma unroll
  for (int cb = 0; cb < 8; ++cb){
    float gv = lng[cb*16 + c0], bv2 = lnb[cb*16 + c0];
    #pragma unroll
    for (int r = 0; r < 4; ++r){
      int orow = rbase + 4*g + r;
      if (orow < N){
        size_t oi = (size_t)orow*DD + cb*16 + c0;
        outT[oi] = (u[cb][r] - mean[r]) * rstd[r] * gv + bv2 + t2f[cb][r];
      }
    }
  }
}

// ---------- fc_x MLP as device fn ----------
__device__ __forceinline__ void mlp2_body(unsigned short* lds, unsigned short* wlds,
    int bid,
    const unsigned short* __restrict__ X,
    const unsigned short* __restrict__ W1, const float* __restrict__ b1,
    const unsigned short* __restrict__ W2, const float* __restrict__ b2,
    const unsigned short* __restrict__ resh, float* __restrict__ outF, int N)
{
  const int tid = threadIdx.x;
  const int w = tid >> 6, l = tid & 63;
  const int g = l >> 4, c0 = l & 15;
  const int swz = (c0 & 7) << 3;
  const int rbase = bid*64 + w*16;

  // prefetch A-frags + residual
  int arow = rbase + c0; if (arow > N-1) arow = N-1;
  const unsigned short* apX = X + (size_t)arow*DD + g*8;
  bf16x8 aX[4];
  #pragma unroll
  for (int kb = 0; kb < 4; ++kb) aX[kb] = *(const bf16x8*)(apX + kb*32);
  unsigned short rs_[8][4];
  #pragma unroll
  for (int cb = 0; cb < 8; ++cb){
    #pragma unroll
    for (int r = 0; r < 4; ++r){
      int orow = rbase + 4*g + r;
      int rc = orow > N-1 ? N-1 : orow;
      rs_[cb][r] = resh[(size_t)rc*DD + cb*16 + c0];
    }
  }
  stage_issue(W1, wlds);
  __syncthreads();

  f32x4 acc[8];
  // ---- GEMM 1 ----
  #pragma unroll
  for (int cb = 0; cb < 8; ++cb) acc[cb] = 0.f;
  gemm_reg(aX, c0, g, swz, wlds, acc);
  __syncthreads();                    // done reading W1
  stage_issue(W2, wlds);
  #pragma unroll
  for (int cb = 0; cb < 8; ++cb){
    float bv = b1[cb*16 + c0];
    #pragma unroll
    for (int r = 0; r < 4; ++r)
      lds[(w*16 + 4*g + r)*LSTR + cb*16 + c0] = f2b(fmaxf(acc[cb][r] + bv, 0.f));
  }
  __syncthreads();                    // W2 ready, h written

  // ---- GEMM 2 ----
  #pragma unroll
  for (int cb = 0; cb < 8; ++cb) acc[cb] = 0.f;
  gemm_lds(lds, w, c0, g, swz, wlds, acc);

  #pragma unroll
  for (int cb = 0; cb < 8; ++cb){
    float bv = b2[cb*16 + c0];
    #pragma unroll
    for (int r = 0; r < 4; ++r){
      int orow = rbase + 4*g + r;
      if (orow < N){
        size_t oi = (size_t)orow*DD + cb*16 + c0;
        outF[oi] = acc[cb][r] + bv + b2f(rs_[cb][r]);
      }
    }
  }
}

// ---------- fused tail: [0,gg) chainT ; [gg,2gg) fc_x ----------
__global__ __launch_bounds__(256, 3) void k_tail(
    const unsigned short* __restrict__ hA, const unsigned short* __restrict__ hB,
    const unsigned short* __restrict__ xh, const unsigned short* __restrict__ th,
    const unsigned short* __restrict__ wt,
    const float* __restrict__ b1a, const float* __restrict__ b2a,
    const float* __restrict__ b1b, const float* __restrict__ b2b,
    const float* __restrict__ bo,  const float* __restrict__ lng,
    const float* __restrict__ lnb, const float* __restrict__ bf1,
    const float* __restrict__ bf2,
    float* __restrict__ outX, float* __restrict__ outT, int N, int gg)
{
  __shared__ unsigned short lds[64*LSTR];     // 17408 B  h/intermediate tiles (wave-private rows)
  __shared__ unsigned short wlds[DD*DD];      // 32768 B  linear weight image (pre-swizzled)
  const unsigned short* W1a = wt + 0*DD*DD;
  const unsigned short* W2a = wt + 1*DD*DD;
  const unsigned short* W1b = wt + 2*DD*DD;
  const unsigned short* W2b = wt + 3*DD*DD;
  const unsigned short* Wo  = wt + 4*DD*DD;
  const unsigned short* Wf1 = wt + 5*DD*DD;
  const unsigned short* Wf2 = wt + 6*DD*DD;
  if (blockIdx.x < (unsigned)gg){
    chainT_body(lds, wlds, blockIdx.x, hA, hB, W1a, b1a, W2a, b2a, W1b, b1b, W2b, b2b,
                Wo, bo, th, lng, lnb, outT, N);
  } else {
    mlp2_body(lds, wlds, blockIdx.x - gg, xh, Wf1, bf1, Wf2, bf2, xh, outX, N);
  }
}

extern "C" void kernel_launch(void* const* d_in, const int* in_sizes, int n_in,
                              void* d_out, int out_size, void* d_ws, size_t ws_size,
                              hipStream_t stream) {
  const float* x     = (const float*)d_in[0];
  const float* t     = (const float*)d_in[1];
  const int*   e_t   = (const int*)d_in[2];
  const int*   e_xct = (const int*)d_in[3];
  const float* b1a = (const float*)d_in[5];
  const float* b2a = (const float*)d_in[7];
  const float* b1b = (const float*)d_in[9];
  const float* b2b = (const float*)d_in[11];
  const float* bo  = (const float*)d_in[13];
  const float* lng = (const float*)d_in[14];
  const float* lnb = (const float*)d_in[15];
  const float* bf1 = (const float*)d_in[17];
  const float* bf2 = (const float*)d_in[19];

  const int N = in_sizes[0] / DD;     // 50000
  const int E = in_sizes[2] / 2;      // 1600000
  const int NBper = (N + 127) >> BSH; // 391
  const int NB2 = 2*NBper;            // 782

  // ---- workspace carve ----
  char* p = (char*)d_ws;
  auto carve = [&](size_t b)->char*{ char* r = p; p += (b + 255) & ~(size_t)255; return r; };
  size_t nd2z = (size_t)(N+1)*DD*2;   // +1 zero row (ZROW) for gather sources
  size_t nd2 = (size_t)N*DD*2, nd4 = (size_t)N*DD*4;
  unsigned short* xh = (unsigned short*)carve(nd2z);
  unsigned short* th = (unsigned short*)carve(nd2z);
  unsigned short* hA = (unsigned short*)carve(nd2);
  unsigned short* hB = (unsigned short*)carve(nd2);
  float*          pA = (float*)carve(nd4);            // gbucket alias only
  unsigned short* wt = (unsigned short*)carve((size_t)7*DD*DD*2);
  int* gbcount = (int*)carve((size_t)NB2*4);
  int* gbase   = (int*)carve((size_t)(NB2+1)*4);
  int* gcursor = (int*)carve((size_t)NB2*4);
  int* offs    = (int*)carve((size_t)2*(N+1)*4);
  unsigned short* csr = (unsigned short*)carve((size_t)2*E*2);
  unsigned* gbucket = (unsigned*)pA;                  // 2E*4 = 12.8MB <= nd4 (25.6MB)

  float* outX = (float*)d_out;
  float* outT = outX + (size_t)N*DD;

  hipMemsetAsync(gbcount, 0, (size_t)NB2*4, stream);

  WP wp;
  wp.w[0] = (const float*)d_in[4];  wp.w[1] = (const float*)d_in[6];
  wp.w[2] = (const float*)d_in[8];  wp.w[3] = (const float*)d_in[10];
  wp.w[4] = (const float*)d_in[12]; wp.w[5] = (const float*)d_in[16];
  wp.w[6] = (const float*)d_in[18];

  const int M4 = N*DD/4;
  const int ncv = (2*M4 + 255)/256;
  k_pre<<<ncv + 8 + 256, 256, 0, stream>>>(x, t, (unsigned*)xh, (unsigned*)th, M4,
                                           wp, wt, e_t, e_xct, gbcount, E, NBper, ncv, N);
  k_bscan<<<1, 1024, 0, stream>>>(gbcount, gbase, gcursor, NB2, 2*E);
  const int nsc = (int)((2L*E + SCCH-1) / SCCH);
  k_scatter<<<nsc, 256, 0, stream>>>(e_t, e_xct, gcursor, gbucket, E, NBper);
  k_build<<<NB2, 256, 0, stream>>>(gbucket, gbase, offs, csr, N, E, NBper);
  k_gather<<<(2*N + 3)/4, 256, 0, stream>>>(th, xh, offs, csr, hA, hB, N, E);

  const int gg = (N + 63)/64;
  k_tail<<<2*gg, 256, 0, stream>>>(hA, hB, xh, th, wt, b1a, b2a, b1b, b2b, bo,
                                   lng, lnb, bf1, bf2, outX, outT, N, gg);
}